// Round 2
// baseline (339.757 us; speedup 1.0000x reference)
//
#include <hip/hip_runtime.h>

#define NROWS  32768
#define DIM    64
#define KCODES 1024
#define NELEM  (NROWS * DIM)   // 2097152
#define CHUNKS 8
#define CPC    (KCODES / CHUNKS)   // 128 codes per chunk-block

typedef float v2f __attribute__((ext_vector_type(2)));

// numpy-style pairwise sum of squares for n=64 contiguous fp32 (contraction
// OFF so the squared temps are not fused into the adds; matches jnp.sum(x*x)).
__device__ __forceinline__ float np_sumsq64(const float v[64]) {
#pragma clang fp contract(off)
  float r0 = v[0] * v[0];
  float r1 = v[1] * v[1];
  float r2 = v[2] * v[2];
  float r3 = v[3] * v[3];
  float r4 = v[4] * v[4];
  float r5 = v[5] * v[5];
  float r6 = v[6] * v[6];
  float r7 = v[7] * v[7];
#pragma unroll
  for (int i = 8; i < 64; i += 8) {
    r0 += v[i + 0] * v[i + 0];
    r1 += v[i + 1] * v[i + 1];
    r2 += v[i + 2] * v[i + 2];
    r3 += v[i + 3] * v[i + 3];
    r4 += v[i + 4] * v[i + 4];
    r5 += v[i + 5] * v[i + 5];
    r6 += v[i + 6] * v[i + 6];
    r7 += v[i + 7] * v[i + 7];
  }
  return ((r0 + r1) + (r2 + r3)) + ((r4 + r5) + (r6 + r7));
}

// DPP quad_perm [1,0,3,2]: swap lane pairs (2t <-> 2t+1). VALU-only, no LDS.
__device__ __forceinline__ float swap_pair(float v) {
  return __int_as_float(
      __builtin_amdgcn_mov_dpp(__float_as_int(v), 0xB1, 0xF, 0xF, true));
}

// Phase 1 (grid 128x256, one thread per row): init keys, zero loss+counter,
// per-row ||x||^2, per-code ||e||^2 (first 1024 threads).
__global__ __launch_bounds__(256) void vq_prep(const float* __restrict__ x,
                                               const float* __restrict__ w,
                                               float* __restrict__ se,
                                               float* __restrict__ sxv,
                                               unsigned long long* __restrict__ keys,
                                               double* __restrict__ loss,
                                               unsigned int* __restrict__ cnt) {
  const int t = blockIdx.x * 256 + threadIdx.x;  // 0..32767
  if (t == 0) { *loss = 0.0; *cnt = 0u; }
  keys[t] = ~0ull;

  float v[64];
  const float4* xr = (const float4*)(x + (size_t)t * DIM);
#pragma unroll
  for (int i = 0; i < 16; ++i) {
    float4 q = xr[i];
    v[4 * i + 0] = q.x; v[4 * i + 1] = q.y;
    v[4 * i + 2] = q.z; v[4 * i + 3] = q.w;
  }
  sxv[t] = np_sumsq64(v);

  if (t < KCODES) {
    const float4* wr = (const float4*)(w + (size_t)t * DIM);
#pragma unroll
    for (int i = 0; i < 16; ++i) {
      float4 q = wr[i];
      v[4 * i + 0] = q.x; v[4 * i + 1] = q.y;
      v[4 * i + 2] = q.z; v[4 * i + 3] = q.w;
    }
    se[t] = np_sumsq64(v);
  }
}

// Phase 2: distances + argmin, HALF-ROW threads (2 threads per row).
// Rationale (round-2 post-mortem): full-row threads need 64 VGPRs of x
// resident, but full residency (8 waves/SIMD, grid 2048 = 8 blocks/CU) caps
// waves at 64 VGPRs total -> the compiler rematerialized x inside the code
// loop (VGPR_Count=48 observed), thrashing vL1/L2 every iteration. Half-row
// needs only 32 VGPRs of x -> genuinely resident under (256,8).
//
// Split preserves the verified summation tree EXACTLY: even lane (h=0)
// accumulates a0,a1 over even float4s -> mine = a0+a1 = s01; odd lane (h=1)
// accumulates a2,a3 over odd float4s -> mine = a2+a3 = s23. One DPP
// quad-perm swap exchanges mine across the lane pair; s = mine+other equals
// s01+s23 bitwise in both lanes (IEEE add is bitwise-commutative). Then
// dot = s.x+s.y, d = fma(-2, dot, sx+se[c]) — identical fp sequence to the
// absmax-0.0-verified full-row kernel.
//
// w goes on the VECTOR path (address depends on h -> per-lane global_load),
// 8x16B per code per lane; the lane pair covers 32 contiguous bytes so a
// wave-load touches one 64B line. Swizzle: XCD x = bid&7 (hw round-robin),
// j = bid>>3; chunk = (j>>3)&7 so blocks co-resident on a CU share the same
// 32 KB w-chunk (exact under block-packed dispatch, 2 chunks under CU
// round-robin) -> w stays vL1-resident; se via scalar path (uniform).
// Grid 2048 = 256 row-groups (128 rows) x 8 chunks (128 codes) = exactly
// 8 blocks/CU, one clean residency round.
__global__ __launch_bounds__(256, 8) void vq_dist(const float* __restrict__ x,
                                                  const float* __restrict__ w,
                                                  const float* __restrict__ se,
                                                  const float* __restrict__ sxv,
                                                  unsigned long long* __restrict__ keys) {
  const int bid = blockIdx.x;
  const int xcd = bid & 7;
  const int j = bid >> 3;                       // 0..255 within XCD
  const int chunk = (j >> 3) & 7;               // same-CU blocks share chunk
  const int group = (xcd << 5) + (j & 7) + ((j >> 6) << 3);  // bijective
  const int t = threadIdx.x;
  const int h = t & 1;                          // half: 0 = even float4s
  const int row = group * 128 + (t >> 1);

  // Load my half of the row: float4s {2k+h}, k=0..7 (32 floats = 32 VGPRs).
  v2f xh[16];
  const float4* xr = (const float4*)(x + (size_t)row * DIM);
#pragma unroll
  for (int k = 0; k < 8; ++k) {
    float4 q = xr[2 * k + h];
    xh[2 * k + 0] = (v2f){q.x, q.y};
    xh[2 * k + 1] = (v2f){q.z, q.w};
  }
#pragma unroll
  for (int i = 0; i < 16; ++i) asm volatile("" : "+v"(xh[i]));
  const float sx = sxv[row];

  const int c0 = chunk * CPC;
  float bd = __builtin_inff();
  int bc = 0;

#pragma unroll 2
  for (int jj = 0; jj < CPC; ++jj) {
    const int c = c0 + jj;
    // lane's float4 stream: w row c, float4s {2k+h}
    const float4* wr = (const float4*)(w + (size_t)c * DIM) + h;
    v2f aA = (v2f){0.f, 0.f}, aB = (v2f){0.f, 0.f};
#pragma unroll
    for (int k = 0; k < 8; ++k) {
      float4 q = wr[2 * k];
      aA += (v2f){q.x, q.y} * xh[2 * k + 0];   // == a0 (h=0) / a2 (h=1)
      aB += (v2f){q.z, q.w} * xh[2 * k + 1];   // == a1 (h=0) / a3 (h=1)
    }
    v2f mine = aA + aB;                        // s01 (h=0) or s23 (h=1)
    v2f oth;
    oth.x = swap_pair(mine.x);
    oth.y = swap_pair(mine.y);
    v2f s = mine + oth;                        // bitwise == s01 + s23
    float dot = s.x + s.y;
    float d = fmaf(-2.0f, dot, sx + se[c]);
    if (d < bd) { bd = d; bc = c; }
  }

  if (h == 0) {
    unsigned long long key =
        ((unsigned long long)__float_as_uint(bd) << 32) | (unsigned long long)(unsigned)bc;
    atomicMin(&keys[row], key);
  }
}

// Phase 3 (grid 1024x256, 32 rows/block): decode key -> index, write indices
// (as float), STE quantized output x + fl(w - x), fp64 loss partial; fused
// finalization via last-block pattern (saves a launch).
__global__ __launch_bounds__(256) void vq_out(const float* __restrict__ x,
                                              const float* __restrict__ w,
                                              const unsigned long long* __restrict__ keys,
                                              float* __restrict__ outq,
                                              float* __restrict__ outidx,
                                              double* __restrict__ loss,
                                              unsigned int* __restrict__ cnt,
                                              float* __restrict__ outloss) {
  __shared__ int sidx[32];
  __shared__ double sp[4];
  const int b = blockIdx.x, t = threadIdx.x;

  if (t < 32) {
    const int row = b * 32 + t;
    unsigned long long k = keys[row];
    const int idx = (int)(unsigned int)(k & 0xFFFFFFFFull);
    outidx[row] = (float)idx;
    sidx[t] = idx;
  }
  __syncthreads();

  double acc = 0.0;
  const float4* x4 = (const float4*)x;
  float4* o4 = (float4*)outq;
#pragma unroll
  for (int i = 0; i < 2; ++i) {
    const int e = i * 256 + t;          // 0..511 float4s of this block's rows
    const int rl = e >> 4;              // local row (0..31)
    const int d4 = e & 15;              // float4 within the row
    const size_t gofs = ((size_t)b * 32 + rl) * 16 + d4;
    float4 xvv = x4[gofs];
    const float4* wr = (const float4*)(w + (size_t)sidx[rl] * DIM);
    float4 wv = wr[d4];
    float tx = wv.x - xvv.x, ty = wv.y - xvv.y;
    float tz = wv.z - xvv.z, tw = wv.w - xvv.w;
    float4 q;
    q.x = xvv.x + tx; q.y = xvv.y + ty;   // ref STE: x + fl(q - x)
    q.z = xvv.z + tz; q.w = xvv.w + tw;
    o4[gofs] = q;
    acc += (double)tx * tx + (double)ty * ty + (double)tz * tz + (double)tw * tw;
  }

#pragma unroll
  for (int s = 32; s > 0; s >>= 1) acc += __shfl_down(acc, s, 64);
  if ((t & 63) == 0) sp[t >> 6] = acc;
  __syncthreads();
  if (t == 0) {
    atomicAdd(loss, (sp[0] + sp[1]) + (sp[2] + sp[3]));
    __threadfence();
    unsigned int old = atomicAdd(cnt, 1u);
    if (old == 1023u) {
      double total = atomicAdd(loss, 0.0);   // L2 read, sees all prior adds
      *outloss = 0.5f * (float)(total / (double)NELEM);
    }
  }
}

extern "C" void kernel_launch(void* const* d_in, const int* in_sizes, int n_in,
                              void* d_out, int out_size, void* d_ws, size_t ws_size,
                              hipStream_t stream) {
  const float* x = (const float*)d_in[0];   // inputs (32,64,32,32) fp32
  const float* w = (const float*)d_in[1];   // weight (1024,64) fp32

  float* outq    = (float*)d_out;           // [0, 2097152)
  float* outidx  = outq + NELEM;            // [2097152, +32768)
  float* outloss = outidx + NROWS;          // [2129920]

  char* wsb = (char*)d_ws;
  double* loss      = (double*)wsb;                                 // 8 B
  unsigned int* cnt = (unsigned int*)(wsb + 64);                    // 4 B
  float* se    = (float*)(wsb + 256);                               // 4 KB
  float* sxv   = (float*)(wsb + 8192);                              // 128 KB
  unsigned long long* keys = (unsigned long long*)(wsb + 147456);   // 256 KB

  hipLaunchKernelGGL(vq_prep, dim3(128),  dim3(256), 0, stream, x, w, se, sxv, keys, loss, cnt);
  hipLaunchKernelGGL(vq_dist, dim3(2048), dim3(256), 0, stream, x, w, se, sxv, keys);
  hipLaunchKernelGGL(vq_out,  dim3(1024), dim3(256), 0, stream, x, w, keys, outq, outidx, loss, cnt, outloss);
}

// Round 3
// 170.832 us; speedup vs baseline: 1.9888x; 1.9888x over previous
//
#include <hip/hip_runtime.h>

#define NROWS  32768
#define DIM    64
#define KCODES 1024
#define NELEM  (NROWS * DIM)   // 2097152
#define CHUNKS 8
#define CPC    (KCODES / CHUNKS)   // 128 codes per chunk-block

typedef float v2f __attribute__((ext_vector_type(2)));

// numpy-style pairwise sum of squares for n=64 contiguous fp32 (contraction
// OFF so the squared temps are not fused into the adds; matches jnp.sum(x*x)).
// Verified absmax 0.0 in prior rounds.
__device__ __forceinline__ float np_sumsq64(const float v[64]) {
#pragma clang fp contract(off)
  float r0 = v[0] * v[0];
  float r1 = v[1] * v[1];
  float r2 = v[2] * v[2];
  float r3 = v[3] * v[3];
  float r4 = v[4] * v[4];
  float r5 = v[5] * v[5];
  float r6 = v[6] * v[6];
  float r7 = v[7] * v[7];
#pragma unroll
  for (int i = 8; i < 64; i += 8) {
    r0 += v[i + 0] * v[i + 0];
    r1 += v[i + 1] * v[i + 1];
    r2 += v[i + 2] * v[i + 2];
    r3 += v[i + 3] * v[i + 3];
    r4 += v[i + 4] * v[i + 4];
    r5 += v[i + 5] * v[i + 5];
    r6 += v[i + 6] * v[i + 6];
    r7 += v[i + 7] * v[i + 7];
  }
  return ((r0 + r1) + (r2 + r3)) + ((r4 + r5) + (r6 + r7));
}

// Init (grid 128x256): keys to +inf, loss/cnt zero, per-code ||e||^2 (first
// 1024 threads). No x pass — vq_dist computes sx from its own row load.
__global__ __launch_bounds__(256) void vq_init(const float* __restrict__ w,
                                               float* __restrict__ se,
                                               unsigned long long* __restrict__ keys,
                                               double* __restrict__ loss,
                                               unsigned int* __restrict__ cnt) {
  const int t = blockIdx.x * 256 + threadIdx.x;  // 0..32767
  if (t == 0) { *loss = 0.0; *cnt = 0u; }
  keys[t] = ~0ull;

  if (t < KCODES) {
    float v[64];
    const float4* wr = (const float4*)(w + (size_t)t * DIM);
#pragma unroll
    for (int i = 0; i < 16; ++i) {
      float4 q = wr[i];
      v[4 * i + 0] = q.x; v[4 * i + 1] = q.y;
      v[4 * i + 2] = q.z; v[4 * i + 3] = q.w;
    }
    se[t] = np_sumsq64(v);
  }
}

// Phase 2: distances + argmin. Full-row threads (x resident), w served from
// LDS BROADCAST.
// Round-2 post-mortems: (a) round-1's VALUBusy 56% at 62.6us == ~35us of
// issued VALU work ~= the 31us fp32-FMA floor -> no instruction bloat; the
// deficit was pure stall on the scalar w-stream (256B/code s_load through the
// small shared K$, thrashed by 4 resident blocks). (b) round-2's per-lane
// vector w-loads were 13x worse (VMEM TA path, VALUBusy 19%). Conclusion: w
// must come from LDS: wave-uniform ds_read_b128 = same-address broadcast,
// conflict-free, ~17 LDS-pipe cycles/code vs 146 VALU cycles/code -> fully
// hidden, and lgkmcnt pipelining over unroll-2 kills the stall.
// Grid 1024 = 128 row-groups (256 rows) x 8 chunks (128 codes); LDS
// 33.3KB/block -> 4 blocks/CU x 4 waves = 16 waves/CU (VGPR ~90 under the
// (256,4) 128-VGPR budget). XCD-bijective swizzle: all 8 chunk-blocks of a
// row-group on one XCD -> the group's 64KB of x is HBM-fetched once.
// fp sequence per code is op-for-op identical to the absmax-0.0 round-1
// kernel: a0..a3 v2f chains over the same element order, ((a0+a1)+(a2+a3)),
// dot=s.x+s.y, d=fma(-2,dot,fl(sx+se[c])); sx via the same np_sumsq64 tree
// on the same values prep used. Tie-break: strict < over ascending c, then
// u64 (dist_bits<<32)|c atomicMin across chunks.
__global__ __launch_bounds__(256, 4) void vq_dist(const float* __restrict__ x,
                                                  const float* __restrict__ w,
                                                  const float* __restrict__ se,
                                                  unsigned long long* __restrict__ keys) {
  __shared__ float wlds[CPC * DIM];   // 32 KB
  __shared__ float se_lds[CPC];       // 512 B
  const int bid = blockIdx.x;
  const int l = (bid & 7) * 128 + (bid >> 3);  // XCD-bijective (1024 = 8*128)
  const int group = l >> 3;                    // 0..127
  const int chunk = l & 7;                     // 0..7
  const int t = threadIdx.x;
  const int row = group * 256 + t;
  const int c0 = chunk * CPC;

  // Stage w chunk -> LDS (one-time 32KB; XCD L2-served after first block).
  float4* wl4 = (float4*)wlds;
  const float4* ws4 = (const float4*)(w + (size_t)c0 * DIM);
#pragma unroll
  for (int k = 0; k < 8; ++k) wl4[t + 256 * k] = ws4[t + 256 * k];
  if (t < CPC) se_lds[t] = se[c0 + t];

  // Own row -> registers; sx with the exact prep tree.
  float v[64];
  const float4* xr = (const float4*)(x + (size_t)row * DIM);
#pragma unroll
  for (int i = 0; i < 16; ++i) {
    float4 q = xr[i];
    v[4 * i + 0] = q.x; v[4 * i + 1] = q.y;
    v[4 * i + 2] = q.z; v[4 * i + 3] = q.w;
  }
  const float sx = np_sumsq64(v);

  __syncthreads();

  float bd = __builtin_inff();
  int bc = 0;

#pragma unroll 2
  for (int j = 0; j < CPC; ++j) {
    const float4* wr = (const float4*)(wlds + j * DIM);  // uniform -> broadcast
    v2f a0 = (v2f){0.f, 0.f}, a1 = (v2f){0.f, 0.f};
    v2f a2 = (v2f){0.f, 0.f}, a3 = (v2f){0.f, 0.f};
#pragma unroll
    for (int i = 0; i < 16; i += 2) {
      float4 t0 = wr[i];        // ds_read_b128
      float4 t1 = wr[i + 1];
      a0 += (v2f){t0.x, t0.y} * (v2f){v[4 * i + 0], v[4 * i + 1]};
      a1 += (v2f){t0.z, t0.w} * (v2f){v[4 * i + 2], v[4 * i + 3]};
      a2 += (v2f){t1.x, t1.y} * (v2f){v[4 * i + 4], v[4 * i + 5]};
      a3 += (v2f){t1.z, t1.w} * (v2f){v[4 * i + 6], v[4 * i + 7]};
    }
    v2f s01 = a0 + a1;
    v2f s23 = a2 + a3;
    v2f s = s01 + s23;
    float dot = s.x + s.y;
    float d = fmaf(-2.0f, dot, sx + se_lds[j]);
    if (d < bd) { bd = d; bc = c0 + j; }
  }

  unsigned long long key =
      ((unsigned long long)__float_as_uint(bd) << 32) | (unsigned long long)(unsigned)bc;
  atomicMin(&keys[row], key);
}

// Phase 3 (grid 1024x256, 32 rows/block): decode key -> index, write indices
// (as float), STE quantized output x + fl(w - x), fp64 loss partial; fused
// finalization via last-block counter (passed verification in round 2).
__global__ __launch_bounds__(256) void vq_out(const float* __restrict__ x,
                                              const float* __restrict__ w,
                                              const unsigned long long* __restrict__ keys,
                                              float* __restrict__ outq,
                                              float* __restrict__ outidx,
                                              double* __restrict__ loss,
                                              unsigned int* __restrict__ cnt,
                                              float* __restrict__ outloss) {
  __shared__ int sidx[32];
  __shared__ double sp[4];
  const int b = blockIdx.x, t = threadIdx.x;

  if (t < 32) {
    const int row = b * 32 + t;
    unsigned long long k = keys[row];
    const int idx = (int)(unsigned int)(k & 0xFFFFFFFFull);
    outidx[row] = (float)idx;
    sidx[t] = idx;
  }
  __syncthreads();

  double acc = 0.0;
  const float4* x4 = (const float4*)x;
  float4* o4 = (float4*)outq;
#pragma unroll
  for (int i = 0; i < 2; ++i) {
    const int e = i * 256 + t;          // 0..511 float4s of this block's rows
    const int rl = e >> 4;              // local row (0..31)
    const int d4 = e & 15;              // float4 within the row
    const size_t gofs = ((size_t)b * 32 + rl) * 16 + d4;
    float4 xvv = x4[gofs];
    const float4* wr = (const float4*)(w + (size_t)sidx[rl] * DIM);
    float4 wv = wr[d4];
    float tx = wv.x - xvv.x, ty = wv.y - xvv.y;
    float tz = wv.z - xvv.z, tw = wv.w - xvv.w;
    float4 q;
    q.x = xvv.x + tx; q.y = xvv.y + ty;   // ref STE: x + fl(q - x)
    q.z = xvv.z + tz; q.w = xvv.w + tw;
    o4[gofs] = q;
    acc += (double)tx * tx + (double)ty * ty + (double)tz * tz + (double)tw * tw;
  }

#pragma unroll
  for (int s = 32; s > 0; s >>= 1) acc += __shfl_down(acc, s, 64);
  if ((t & 63) == 0) sp[t >> 6] = acc;
  __syncthreads();
  if (t == 0) {
    atomicAdd(loss, (sp[0] + sp[1]) + (sp[2] + sp[3]));
    __threadfence();
    unsigned int old = atomicAdd(cnt, 1u);
    if (old == 1023u) {
      double total = atomicAdd(loss, 0.0);   // device-scope read after all adds
      *outloss = 0.5f * (float)(total / (double)NELEM);
    }
  }
}

extern "C" void kernel_launch(void* const* d_in, const int* in_sizes, int n_in,
                              void* d_out, int out_size, void* d_ws, size_t ws_size,
                              hipStream_t stream) {
  const float* x = (const float*)d_in[0];   // inputs (32,64,32,32) fp32
  const float* w = (const float*)d_in[1];   // weight (1024,64) fp32

  float* outq    = (float*)d_out;           // [0, 2097152)
  float* outidx  = outq + NELEM;            // [2097152, +32768)
  float* outloss = outidx + NROWS;          // [2129920]

  char* wsb = (char*)d_ws;
  double* loss      = (double*)wsb;                                 // 8 B
  unsigned int* cnt = (unsigned int*)(wsb + 64);                    // 4 B
  float* se    = (float*)(wsb + 256);                               // 4 KB
  unsigned long long* keys = (unsigned long long*)(wsb + 147456);   // 256 KB

  hipLaunchKernelGGL(vq_init, dim3(128),  dim3(256), 0, stream, w, se, keys, loss, cnt);
  hipLaunchKernelGGL(vq_dist, dim3(1024), dim3(256), 0, stream, x, w, se, keys);
  hipLaunchKernelGGL(vq_out,  dim3(1024), dim3(256), 0, stream, x, w, keys, outq, outidx, loss, cnt, outloss);
}